// Round 9
// baseline (533.700 us; speedup 1.0000x reference)
//
#include <hip/hip_runtime.h>
#include <hip/hip_fp16.h>
#include <hip/hip_cooperative_groups.h>
#include <math.h>

namespace cg = cooperative_groups;

#define NF 32

__device__ __forceinline__ void atomic_pk_add_f16(unsigned int* addr, unsigned int val) {
    asm volatile("global_atomic_pk_add_f16 %0, %1, off" :: "v"(addr), "v"(val) : "memory");
}

// One persistent cooperative kernel: count -> prescale -> scatter -> gate
__global__ __launch_bounds__(256, 4) void fused_kernel(
    const float* __restrict__ x, const int* __restrict__ src, const int* __restrict__ dst,
    const float* __restrict__ Wxz0, const float* __restrict__ Wxz1,
    const float* __restrict__ bxz,  const float* __restrict__ bhz,
    const float* __restrict__ Wxh0, const float* __restrict__ Wxh1,
    const float* __restrict__ bxh,  const float* __restrict__ bhh,
    const float* __restrict__ Wl,   const float* __restrict__ bl,
    float* __restrict__ out,
    int* __restrict__ cnt, unsigned int* __restrict__ acc,
    float* __restrict__ dis, unsigned int* __restrict__ xs,
    int N, int E)
{
    cg::grid_group grid = cg::this_grid();

    __shared__ float sWz0[NF * NF], sWz1[NF * NF], sWh0[NF * NF], sWh1[NF * NF];
    __shared__ float sbz[NF], sbh[NF], sWl[NF];
    __shared__ float sx[8][NF + 1], st[8][NF + 1];

    int t   = threadIdx.x;
    int tid = blockIdx.x * 256 + t;
    int T   = gridDim.x * 256;

    // stage weights once per block (read-only; used only in P4)
    for (int i = t; i < NF * NF; i += 256) {
        sWz0[i] = Wxz0[i];
        sWz1[i] = Wxz1[i];
        sWh0[i] = Wxh0[i];
        sWh1[i] = Wxh1[i];
    }
    if (t < NF) {
        sbz[t] = bxz[t] + bhz[t];
        sbh[t] = bxh[t] + bhh[t];
        sWl[t] = Wl[t];
    }

    // P0: zero cnt
    for (int i = tid; i < N; i += T) cnt[i] = 0;
    grid.sync();

    // P1: out-degree by src
    for (int e = tid; e < E; e += T) atomicAdd(&cnt[src[e]], 1);
    grid.sync();

    // P2: dis = rsqrt(deg); xs = f16x2(dis*x); acc = 0
    int NT = N * 16;
    for (int i = tid; i < NT; i += T) {
        int n  = i >> 4;
        int f2 = i & 15;
        acc[i] = 0u;
        int d = cnt[n];
        float di = (d > 0) ? rsqrtf((float)d) : 0.0f;
        float2 xv = *(const float2*)(x + (size_t)n * NF + f2 * 2);
        unsigned short lo = __half_as_ushort(__float2half(di * xv.x));
        unsigned short hi = __half_as_ushort(__float2half(di * xv.y));
        xs[i] = ((unsigned int)hi << 16) | lo;
        if (f2 == 0) dis[n] = di;
    }
    grid.sync();

    // P3: scatter acc[dst] += xs[src] (packed f16 atomics)
    long long ET = (long long)E * 16;
    for (long long i = tid; i < ET; i += T) {
        int e  = (int)(i >> 4);
        int f2 = (int)(i & 15);
        int s = src[e];
        int d = dst[e];
        unsigned int v = xs[s * 16 + f2];
        atomic_pk_add_f16(&acc[d * 16 + f2], v);
    }
    grid.sync();

    // P4: gates + readout
    const unsigned short* acc16 = (const unsigned short*)acc;
    int nl = t >> 5;
    int f  = t & 31;
    float blv = bl[0];
    int step = gridDim.x * 8;
    for (int node0 = blockIdx.x * 8; node0 < N; node0 += step) {
        int node = node0 + nl;
        __syncthreads();            // protect st/sx from previous iteration's readers
        if (node < N) {
            sx[nl][f] = x[(size_t)node * NF + f];
            float dn = dis[node];
            float av = __half2float(__ushort_as_half(acc16[(size_t)node * NF + f]));
            st[nl][f] = -dn * av;   // tx1 = -dis[dst] * sum(dis[src]*x[src])
        }
        __syncthreads();
        if (node >= N) continue;

        float az = sbz[f];
        float ah = sbh[f];
        #pragma unroll
        for (int k = 0; k < NF; ++k) {
            float xv = sx[nl][k];
            float tv = st[nl][k];
            az += xv * sWz0[k * NF + f] + tv * sWz1[k * NF + f];
            ah += xv * sWh0[k * NF + f] + tv * sWh1[k * NF + f];
        }

        float z  = 1.0f / (1.0f + expf(-az));
        float ht = tanhf(ah);
        float h  = (1.0f - z) * ht;
        float c  = fmaxf(h, 0.0f) * sWl[f];

        #pragma unroll
        for (int m = 16; m >= 1; m >>= 1) c += __shfl_xor(c, m, 64);

        if (f == 0) out[node] = c + blv;
    }
}

extern "C" void kernel_launch(void* const* d_in, const int* in_sizes, int n_in,
                              void* d_out, int out_size, void* d_ws, size_t ws_size,
                              hipStream_t stream) {
    const float* x    = (const float*)d_in[0];
    const int*   edge = (const int*)d_in[1];   // [2, E]: src row then dst row
    const float* Wxz0 = (const float*)d_in[2];
    const float* Wxz1 = (const float*)d_in[3];
    const float* bxz  = (const float*)d_in[4];
    const float* bhz  = (const float*)d_in[7];
    const float* Wxh0 = (const float*)d_in[14];
    const float* Wxh1 = (const float*)d_in[15];
    const float* bxh  = (const float*)d_in[16];
    const float* bhh  = (const float*)d_in[19];
    const float* Wl   = (const float*)d_in[20];
    const float* bl   = (const float*)d_in[21];
    float* out = (float*)d_out;

    int N = in_sizes[0] / NF;
    int E = in_sizes[1] / 2;
    const int* src = edge;
    const int* dst = edge + E;

    // ws (4B elems): cnt[N] | acc[16N] | dis[N] | xs[16N]
    int*          cnt = (int*)d_ws;
    unsigned int* acc = (unsigned int*)(cnt + N);
    float*        dis = (float*)(acc + (size_t)N * 16);
    unsigned int* xs  = (unsigned int*)(dis + N);

    // Size the cooperative grid from the runtime's own occupancy computation
    // (deterministic, non-stream queries — safe under graph capture).
    int dev = 0;
    hipGetDevice(&dev);
    int numCU = 256;
    hipDeviceGetAttribute(&numCU, hipDeviceAttributeMultiprocessorCount, dev);
    int blocksPerCU = 0;
    hipOccupancyMaxActiveBlocksPerMultiprocessor(&blocksPerCU, (const void*)fused_kernel, 256, 0);
    if (blocksPerCU < 1) blocksPerCU = 1;
    int nblocks = numCU * blocksPerCU;
    if (nblocks > 2048) nblocks = 2048;

    void* args[] = {
        (void*)&x, (void*)&src, (void*)&dst,
        (void*)&Wxz0, (void*)&Wxz1, (void*)&bxz, (void*)&bhz,
        (void*)&Wxh0, (void*)&Wxh1, (void*)&bxh, (void*)&bhh,
        (void*)&Wl, (void*)&bl, (void*)&out,
        (void*)&cnt, (void*)&acc, (void*)&dis, (void*)&xs,
        (void*)&N, (void*)&E
    };
    hipLaunchCooperativeKernel((void*)fused_kernel, dim3(nblocks), dim3(256),
                               args, 0, stream);
}

// Round 10
// 216.030 us; speedup vs baseline: 2.4705x; 2.4705x over previous
//
#include <hip/hip_runtime.h>
#include <hip/hip_fp16.h>
#include <math.h>

#define NF 32

__device__ __forceinline__ void atomic_pk_add_f16(unsigned int* addr, unsigned int val) {
    asm volatile("global_atomic_pk_add_f16 %0, %1, off" :: "v"(addr), "v"(val) : "memory");
}

// ---- kernel 1: out-degree by src (for norm) --------------------------------
__global__ void count_kernel(const int* __restrict__ src, int* __restrict__ cnt, int E) {
    int e = blockIdx.x * blockDim.x + threadIdx.x;
    if (e < E) atomicAdd(&cnt[src[e]], 1);
}

// ---- kernel 2: scatter acc[dst] += f16x2(rsqrt(cnt[src]) * x[src]) ---------
// thread per (edge, feature-pair); dis computed inline (cnt[s] >= 1 always)
__global__ void scatter_kernel(const int* __restrict__ src, const int* __restrict__ dst,
                               const int* __restrict__ cnt, const float* __restrict__ x,
                               unsigned int* __restrict__ acc, int E) {
    int t = blockIdx.x * blockDim.x + threadIdx.x;
    int e = t >> 4;
    int f2 = t & 15;
    if (e >= E) return;
    int s = src[e];
    int d = dst[e];
    float di = rsqrtf((float)cnt[s]);
    float2 xv = *(const float2*)(x + (size_t)s * NF + f2 * 2);
    unsigned short lo = __half_as_ushort(__float2half(di * xv.x));
    unsigned short hi = __half_as_ushort(__float2half(di * xv.y));
    atomic_pk_add_f16(&acc[(size_t)d * 16 + f2], ((unsigned int)hi << 16) | lo);
}

// ---- kernel 3: gates + readout (grid-stride; weights staged once/block) ----
#define GATE_BLOCKS 2048
__global__ __launch_bounds__(256) void gate_kernel(
    const float* __restrict__ x, const unsigned short* __restrict__ acc16,
    const int* __restrict__ cnt,
    const float* __restrict__ Wxz0, const float* __restrict__ Wxz1,
    const float* __restrict__ bxz,  const float* __restrict__ bhz,
    const float* __restrict__ Wxh0, const float* __restrict__ Wxh1,
    const float* __restrict__ bxh,  const float* __restrict__ bhh,
    const float* __restrict__ Wl,   const float* __restrict__ bl,
    float* __restrict__ out, int N)
{
    __shared__ float sWz0[NF * NF], sWz1[NF * NF], sWh0[NF * NF], sWh1[NF * NF];
    __shared__ float sbz[NF], sbh[NF], sWl[NF];
    __shared__ float sx[8][NF + 1], st[8][NF + 1];

    int t = threadIdx.x;
    for (int i = t; i < NF * NF; i += 256) {
        sWz0[i] = Wxz0[i];
        sWz1[i] = Wxz1[i];
        sWh0[i] = Wxh0[i];
        sWh1[i] = Wxh1[i];
    }
    if (t < NF) {
        sbz[t] = bxz[t] + bhz[t];
        sbh[t] = bxh[t] + bhh[t];
        sWl[t] = Wl[t];
    }

    int nl = t >> 5;
    int f  = t & 31;
    float blv = bl[0];
    int step = gridDim.x * 8;

    for (int node0 = blockIdx.x * 8; node0 < N; node0 += step) {
        int node = node0 + nl;
        __syncthreads();            // protect st/sx from previous iteration's readers
        if (node < N) {
            sx[nl][f] = x[(size_t)node * NF + f];
            int dgn = cnt[node];
            float dn = (dgn > 0) ? rsqrtf((float)dgn) : 0.0f;
            float av = __half2float(__ushort_as_half(acc16[(size_t)node * NF + f]));
            st[nl][f] = -dn * av;   // tx1 = -dis[dst] * sum(dis[src]*x[src])
        }
        __syncthreads();
        if (node >= N) continue;

        float az = sbz[f];
        float ah = sbh[f];
        #pragma unroll
        for (int k = 0; k < NF; ++k) {
            float xv = sx[nl][k];
            float tv = st[nl][k];
            az += xv * sWz0[k * NF + f] + tv * sWz1[k * NF + f];
            ah += xv * sWh0[k * NF + f] + tv * sWh1[k * NF + f];
        }

        float z  = 1.0f / (1.0f + expf(-az));
        float ht = tanhf(ah);
        float h  = (1.0f - z) * ht;
        float c  = fmaxf(h, 0.0f) * sWl[f];

        #pragma unroll
        for (int m = 16; m >= 1; m >>= 1) c += __shfl_xor(c, m, 64);

        if (f == 0) out[node] = c + blv;
    }
}

extern "C" void kernel_launch(void* const* d_in, const int* in_sizes, int n_in,
                              void* d_out, int out_size, void* d_ws, size_t ws_size,
                              hipStream_t stream) {
    const float* x    = (const float*)d_in[0];
    const int*   edge = (const int*)d_in[1];   // [2, E]: src row then dst row
    const float* Wxz0 = (const float*)d_in[2];
    const float* Wxz1 = (const float*)d_in[3];
    const float* bxz  = (const float*)d_in[4];
    const float* bhz  = (const float*)d_in[7];
    const float* Wxh0 = (const float*)d_in[14];
    const float* Wxh1 = (const float*)d_in[15];
    const float* bxh  = (const float*)d_in[16];
    const float* bhh  = (const float*)d_in[19];
    const float* Wl   = (const float*)d_in[20];
    const float* bl   = (const float*)d_in[21];
    float* out = (float*)d_out;

    int N = in_sizes[0] / NF;
    int E = in_sizes[1] / 2;
    const int* src = edge;
    const int* dst = edge + E;

    // ws (4B elems): cnt[N] | acc[16N]  (both zeroed in one memset)
    int*          cnt = (int*)d_ws;
    unsigned int* acc = (unsigned int*)(cnt + N);

    hipMemsetAsync(d_ws, 0, (size_t)17 * N * sizeof(int), stream);

    count_kernel<<<(E + 255) / 256, 256, 0, stream>>>(src, cnt, E);

    long long stt = (long long)E * 16;
    scatter_kernel<<<(int)((stt + 255) / 256), 256, 0, stream>>>(src, dst, cnt, x, acc, E);

    int gate_blocks = (N + 7) / 8;
    if (gate_blocks > GATE_BLOCKS) gate_blocks = GATE_BLOCKS;
    gate_kernel<<<gate_blocks, 256, 0, stream>>>(
        x, (const unsigned short*)acc, cnt,
        Wxz0, Wxz1, bxz, bhz, Wxh0, Wxh1, bxh, bhh, Wl, bl, out, N);
}

// Round 11
// 169.720 us; speedup vs baseline: 3.1446x; 1.2729x over previous
//
#include <hip/hip_runtime.h>
#include <hip/hip_fp16.h>
#include <math.h>

#define NF 32

typedef _Float16 half8 __attribute__((ext_vector_type(8)));
typedef float f32x4 __attribute__((ext_vector_type(4)));

__device__ __forceinline__ void atomic_pk_add_f16(unsigned int* addr, unsigned int val) {
    asm volatile("global_atomic_pk_add_f16 %0, %1, off" :: "v"(addr), "v"(val) : "memory");
}

// ---- kernel 1: out-degree by src (for norm) --------------------------------
__global__ __launch_bounds__(256) void count_kernel(const int* __restrict__ src,
                                                    int* __restrict__ cnt, int E) {
    int e = blockIdx.x * blockDim.x + threadIdx.x;
    if (e < E) atomicAdd(&cnt[src[e]], 1);
}

// ---- kernel 2: scatter acc[dst] += f16x2(rsqrt(cnt[src]) * x[src]) ---------
__global__ __launch_bounds__(256) void scatter_kernel(
    const int* __restrict__ src, const int* __restrict__ dst,
    const int* __restrict__ cnt, const float* __restrict__ x,
    unsigned int* __restrict__ acc, int E) {
    int t = blockIdx.x * blockDim.x + threadIdx.x;
    int e = t >> 4;
    int f2 = t & 15;
    if (e >= E) return;
    int s = src[e];
    int d = dst[e];
    float di = rsqrtf((float)cnt[s]);
    float2 xv = *(const float2*)(x + (size_t)s * NF + f2 * 2);
    unsigned short lo = __half_as_ushort(__float2half(di * xv.x));
    unsigned short hi = __half_as_ushort(__float2half(di * xv.y));
    atomic_pk_add_f16(&acc[(size_t)d * 16 + f2], ((unsigned int)hi << 16) | lo);
}

// ---- kernel 3: MFMA gates + readout ----------------------------------------
// 256 threads = 4 waves; each wave owns a 16-node tile (block covers 64 nodes).
// az/ah tiles via mfma_f32_16x16x32_f16; weights in VGPR B-frags (no LDS).
__global__ __launch_bounds__(256) void gate_kernel(
    const float* __restrict__ x, const unsigned short* __restrict__ acc16,
    const int* __restrict__ cnt,
    const float* __restrict__ Wxz0, const float* __restrict__ Wxz1,
    const float* __restrict__ bxz,  const float* __restrict__ bhz,
    const float* __restrict__ Wxh0, const float* __restrict__ Wxh1,
    const float* __restrict__ bxh,  const float* __restrict__ bhh,
    const float* __restrict__ Wl,   const float* __restrict__ bl,
    float* __restrict__ out, int N)
{
    int lane = threadIdx.x & 63;
    int wv   = threadIdx.x >> 6;
    int col  = lane & 15;       // B-frag col / A-frag row index
    int g    = lane >> 4;       // k-group: this lane's k slots = g*8 .. g*8+7

    int tile0 = blockIdx.x * 64 + wv * 16;
    if (tile0 >= N) return;     // no __syncthreads in this kernel — safe

    // --- W fragments (per-lane, once per block): element e = W[g*8+e][col+16h]
    half8 bz0[2], bz1[2], bh0[2], bh1[2];
    #pragma unroll
    for (int h = 0; h < 2; ++h) {
        int c = col + 16 * h;
        #pragma unroll
        for (int e = 0; e < 8; ++e) {
            int k = g * 8 + e;
            bz0[h][e] = (_Float16)Wxz0[k * NF + c];
            bz1[h][e] = (_Float16)Wxz1[k * NF + c];
            bh0[h][e] = (_Float16)Wxh0[k * NF + c];
            bh1[h][e] = (_Float16)Wxh1[k * NF + c];
        }
    }
    float bz_c[2], bh_c[2], wl_c[2];
    #pragma unroll
    for (int h = 0; h < 2; ++h) {
        int c = col + 16 * h;
        bz_c[h] = bxz[c] + bhz[c];
        bh_c[h] = bxh[c] + bhh[c];
        wl_c[h] = Wl[c];
    }
    float bl0 = bl[0];

    // --- A fragments: row = tile0+col, k slots g*8..g*8+7
    int row = tile0 + col;
    int rc  = (row < N) ? row : (N - 1);
    const float* xr = x + (size_t)rc * NF + g * 8;
    float4 xa = *(const float4*)xr;
    float4 xb = *(const float4*)(xr + 4);
    half8 ax;
    ax[0] = (_Float16)xa.x; ax[1] = (_Float16)xa.y;
    ax[2] = (_Float16)xa.z; ax[3] = (_Float16)xa.w;
    ax[4] = (_Float16)xb.x; ax[5] = (_Float16)xb.y;
    ax[6] = (_Float16)xb.z; ax[7] = (_Float16)xb.w;

    int dg = cnt[rc];
    float mdn = (dg > 0) ? -rsqrtf((float)dg) : 0.0f;
    const unsigned short* ar = acc16 + (size_t)rc * NF + g * 8;
    uint4 av = *(const uint4*)ar;
    half8 at;
    {
        __half2 p;
        p = *(__half2*)&av.x; at[0] = (_Float16)(mdn * __half2float(p.x)); at[1] = (_Float16)(mdn * __half2float(p.y));
        p = *(__half2*)&av.y; at[2] = (_Float16)(mdn * __half2float(p.x)); at[3] = (_Float16)(mdn * __half2float(p.y));
        p = *(__half2*)&av.z; at[4] = (_Float16)(mdn * __half2float(p.x)); at[5] = (_Float16)(mdn * __half2float(p.y));
        p = *(__half2*)&av.w; at[6] = (_Float16)(mdn * __half2float(p.x)); at[7] = (_Float16)(mdn * __half2float(p.y));
    }

    // --- MFMAs: az = x@Wz0 + t@Wz1 + bias ; ah = x@Wh0 + t@Wh1 + bias -------
    f32x4 az[2], ah[2];
    #pragma unroll
    for (int h = 0; h < 2; ++h) {
        az[h] = (f32x4){bz_c[h], bz_c[h], bz_c[h], bz_c[h]};
        ah[h] = (f32x4){bh_c[h], bh_c[h], bh_c[h], bh_c[h]};
        az[h] = __builtin_amdgcn_mfma_f32_16x16x32_f16(ax, bz0[h], az[h], 0, 0, 0);
        az[h] = __builtin_amdgcn_mfma_f32_16x16x32_f16(at, bz1[h], az[h], 0, 0, 0);
        ah[h] = __builtin_amdgcn_mfma_f32_16x16x32_f16(ax, bh0[h], ah[h], 0, 0, 0);
        ah[h] = __builtin_amdgcn_mfma_f32_16x16x32_f16(at, bh1[h], ah[h], 0, 0, 0);
    }

    // --- epilogue: per element (node = tile0 + g*4 + j, f = col + 16h) ------
    #pragma unroll
    for (int j = 0; j < 4; ++j) {
        float c = 0.0f;
        #pragma unroll
        for (int h = 0; h < 2; ++h) {
            float z  = 1.0f / (1.0f + __expf(-az[h][j]));
            float ht = tanhf(ah[h][j]);
            float hh = (1.0f - z) * ht;
            c += fmaxf(hh, 0.0f) * wl_c[h];
        }
        // reduce over the 16 f-columns (lanes sharing g)
        #pragma unroll
        for (int m = 8; m >= 1; m >>= 1) c += __shfl_xor(c, m, 64);
        int node = tile0 + g * 4 + j;
        if (col == 0 && node < N) out[node] = c + bl0;
    }
}

extern "C" void kernel_launch(void* const* d_in, const int* in_sizes, int n_in,
                              void* d_out, int out_size, void* d_ws, size_t ws_size,
                              hipStream_t stream) {
    const float* x    = (const float*)d_in[0];
    const int*   edge = (const int*)d_in[1];   // [2, E]: src row then dst row
    const float* Wxz0 = (const float*)d_in[2];
    const float* Wxz1 = (const float*)d_in[3];
    const float* bxz  = (const float*)d_in[4];
    const float* bhz  = (const float*)d_in[7];
    const float* Wxh0 = (const float*)d_in[14];
    const float* Wxh1 = (const float*)d_in[15];
    const float* bxh  = (const float*)d_in[16];
    const float* bhh  = (const float*)d_in[19];
    const float* Wl   = (const float*)d_in[20];
    const float* bl   = (const float*)d_in[21];
    float* out = (float*)d_out;

    int N = in_sizes[0] / NF;
    int E = in_sizes[1] / 2;
    const int* src = edge;
    const int* dst = edge + E;

    // ws (4B elems): cnt[N] | acc[16N]  (both zeroed in one memset)
    int*          cnt = (int*)d_ws;
    unsigned int* acc = (unsigned int*)(cnt + N);

    hipMemsetAsync(d_ws, 0, (size_t)17 * N * sizeof(int), stream);

    count_kernel<<<(E + 255) / 256, 256, 0, stream>>>(src, cnt, E);

    long long stt = (long long)E * 16;
    scatter_kernel<<<(int)((stt + 255) / 256), 256, 0, stream>>>(src, dst, cnt, x, acc, E);

    gate_kernel<<<(N + 63) / 64, 256, 0, stream>>>(
        x, (const unsigned short*)acc, cnt,
        Wxz0, Wxz1, bxz, bhz, Wxh0, Wxh1, bxh, bhh, Wl, bl, out, N);
}